// Round 6
// baseline (314.014 us; speedup 1.0000x reference)
//
#include <hip/hip_runtime.h>
#include <hip/hip_bf16.h>
#include <math.h>
#include <stdint.h>

#define BATCH 2
#define SEQ   2048
#define DMODEL 1024
#define NHEAD 16
#define HDIM  64
#define NROWS (BATCH*SEQ)          // 4096
#define EPS   1e-6f
#define QSCALE 0.1803368801111204f // 0.125 * log2(e): softmax in exp2 domain

typedef float f32x4 __attribute__((ext_vector_type(4)));
typedef short s16x8 __attribute__((ext_vector_type(8)));

// ws layout (ushort units):
//  xq @ 0            (4194304)  -> reused as ab (attention out) after projections
//  xk @ 4194304      -> xk+xv region reused as oproj fp32 partial 0 (16 MB)
//  xv @ 8388608
//  wq @ 12582912     (1048576 each)
//  wk @ 13631488
//  wv @ 14680064
//  wo @ 15728640
//  qb @ 16777216     [B,H,S,64] bf16, pre-scaled by QSCALE
//                    -> qb+kb region reused as oproj fp32 partial 1 (16 MB)
//  kb @ 20971520     [B,H,S,64] bf16
//  vt @ 25165824     [B,H,64,S] bf16 (V transposed)
//  cmask @ 29360128  (1 MB): [B][32 kblocks][S] uint64 bitmask
//  msum  @ 29884416  (128 B): [B][16 qb128] uint32, bit kb = "has masked"
#define OFF_XQ 0
#define OFF_XK 4194304
#define OFF_XV 8388608
#define OFF_WQ 12582912
#define OFF_WK 13631488
#define OFF_WV 14680064
#define OFF_WO 15728640
#define OFF_QB 16777216
#define OFF_KB 20971520
#define OFF_VT 25165824
#define OFF_CM 29360128
#define OFF_MS 29884416

__device__ __forceinline__ unsigned short f2bf(float x) {
    unsigned int u = __builtin_bit_cast(unsigned int, x);
    u += 0x7fff + ((u >> 16) & 1);            // round-to-nearest-even
    return (unsigned short)(u >> 16);
}

__device__ __forceinline__ void gl_lds16(const void* g, void* l) {
    __builtin_amdgcn_global_load_lds(
        (const __attribute__((address_space(1))) unsigned int*)g,
        (__attribute__((address_space(3))) unsigned int*)(unsigned int)(unsigned long long)l,
        16, 0, 0);
}

// ---------------------------------------------------------------------------
// fused fp32 -> bf16 convert of q/k/v + 4 weights, PLUS mask compression
// (blocks >= 16384 do the mask; msum zero-init via hipMemsetAsync before)
// ---------------------------------------------------------------------------
__global__ __launch_bounds__(256) void conv_all_kernel(
    const float* __restrict__ q, const float* __restrict__ k, const float* __restrict__ v,
    const float* __restrict__ wq, const float* __restrict__ wk, const float* __restrict__ wv,
    const float* __restrict__ wo, unsigned short* __restrict__ ws,
    const int* __restrict__ mask, unsigned long long* __restrict__ cm,
    unsigned int* __restrict__ msum)
{
    if (blockIdx.x >= 16384) {
        int t = (blockIdx.x - 16384) * 256 + threadIdx.x;  // [0, 2*32*2048)
        int s  = t & 2047;
        int kb = (t >> 11) & 31;
        int b  = t >> 16;
        const int* mp = mask + ((size_t)b * SEQ + s) * SEQ + kb * 64;
        unsigned long long bits = 0;
        #pragma unroll
        for (int i = 0; i < 16; i++) {
            int4 m4 = *(const int4*)&mp[i * 4];
            unsigned long long nib =
                (unsigned long long)((m4.x != 0) | ((m4.y != 0) << 1) |
                                     ((m4.z != 0) << 2) | ((m4.w != 0) << 3));
            bits |= nib << (i * 4);
        }
        cm[((size_t)b * 32 + kb) * SEQ + s] = bits;
        if (bits != ~0ull)
            atomicOr(&msum[(b << 4) | (s >> 7)], 1u << kb);
        return;
    }
    size_t t = ((size_t)blockIdx.x * 256 + threadIdx.x) * 4;
    const float* src; unsigned short* dst; size_t off;
    if (t < 4194304)       { src = q;  dst = ws + OFF_XQ; off = t; }
    else if (t < 8388608)  { src = k;  dst = ws + OFF_XK; off = t - 4194304; }
    else if (t < 12582912) { src = v;  dst = ws + OFF_XV; off = t - 8388608; }
    else if (t < 13631488) { src = wq; dst = ws + OFF_WQ; off = t - 12582912; }
    else if (t < 14680064) { src = wk; dst = ws + OFF_WK; off = t - 13631488; }
    else if (t < 15728640) { src = wv; dst = ws + OFF_WV; off = t - 14680064; }
    else                   { src = wo; dst = ws + OFF_WO; off = t - 15728640; }
    float4 x = *(const float4*)&src[off];
    ushort4 o;
    o.x = f2bf(x.x); o.y = f2bf(x.y); o.z = f2bf(x.z); o.w = f2bf(x.w);
    *(ushort4*)&dst[off] = o;
}

// ---------------------------------------------------------------------------
// Shared GEMM tile body over K range [kbeg, kend): C[128x128] += A * W^T.
// A,W row-major bf16 with K stride 1024. Per-wave 64x64 = 4x4 C-frags.
// ---------------------------------------------------------------------------
__device__ __forceinline__ void gemm_body(
    const unsigned short* A, const unsigned short* W, int r0, int c0,
    int kbeg, int kend, unsigned short* As, unsigned short* Bs, f32x4 acc[4][4])
{
    const int tid  = threadIdx.x;
    const int wave = tid >> 6, lane = tid & 63;
    const int quad = lane >> 4, l15 = lane & 15;
    const int wr = wave >> 1, wc = wave & 1;
    for (int k0 = kbeg; k0 < kend; k0 += 64) {
        __syncthreads();
        #pragma unroll
        for (int r = 0; r < 4; r++) {
            int f = r * 4096 + tid * 16;      // byte offset in 16KB tile
            int row = f >> 7, cb = f & 127;
            gl_lds16((const char*)A + (size_t)(r0 + row) * 2048 + k0 * 2 + cb,
                     (char*)As + r * 4096 + wave * 1024);
            gl_lds16((const char*)W + (size_t)(c0 + row) * 2048 + k0 * 2 + cb,
                     (char*)Bs + r * 4096 + wave * 1024);
        }
        __syncthreads();
        #pragma unroll
        for (int ks = 0; ks < 2; ks++) {
            s16x8 a[4], b[4];
            #pragma unroll
            for (int mt = 0; mt < 4; mt++)
                a[mt] = *(const s16x8*)((const char*)As + (wr*64 + mt*16 + l15) * 128 + ks*64 + quad*16);
            #pragma unroll
            for (int nt = 0; nt < 4; nt++)
                b[nt] = *(const s16x8*)((const char*)Bs + (wc*64 + nt*16 + l15) * 128 + ks*64 + quad*16);
            #pragma unroll
            for (int mt = 0; mt < 4; mt++)
                #pragma unroll
                for (int nt = 0; nt < 4; nt++)
                    acc[mt][nt] = __builtin_amdgcn_mfma_f32_16x16x32_bf16(a[mt], b[nt], acc[mt][nt], 0, 0, 0);
        }
    }
}

// ---------------------------------------------------------------------------
// QKV projections: z=0 -> q (scaled, [B,H,S,d]), z=1 -> k ([B,H,S,d]),
// z=2 -> V^T computed DIRECTLY as Wv * X^T (operand swap, coalesced stores).
// ---------------------------------------------------------------------------
__global__ __launch_bounds__(256) void qkv_gemm_kernel(
    unsigned short* __restrict__ ws,
    const float* __restrict__ bq, const float* __restrict__ bk, const float* __restrict__ bv)
{
    __shared__ __align__(16) unsigned short As[8192];
    __shared__ __align__(16) unsigned short Bs[8192];
    const int z = blockIdx.z;
    const unsigned short *A, *W;
    int r0, c0;
    if (z != 2) {
        A = ws + (size_t)z * 4194304;            // xq/xk
        W = ws + OFF_WQ + (size_t)z * 1048576;
        r0 = blockIdx.x * 128; c0 = blockIdx.y * 128;
    } else {
        A = ws + OFF_WV;                         // rows = output features
        W = ws + OFF_XV;                         // "cols" = seq rows
        r0 = blockIdx.y * 128; c0 = blockIdx.x * 128;
    }
    const float* bias = (z == 0) ? bq : (z == 1 ? bk : bv);
    unsigned short* outp = ws + OFF_QB + (size_t)z * 4194304;      // qb/kb/vt
    const float scale = (z == 0) ? QSCALE : 1.0f;

    f32x4 acc[4][4] = {};
    gemm_body(A, W, r0, c0, 0, DMODEL, As, Bs, acc);

    const int lane = threadIdx.x & 63, wave = threadIdx.x >> 6;
    const int quad = lane >> 4, l15 = lane & 15;
    const int wr = wave >> 1, wc = wave & 1;
    if (z != 2) {
        float bias_v[4];
        #pragma unroll
        for (int nt = 0; nt < 4; nt++) bias_v[nt] = bias[c0 + wc*64 + nt*16 + l15];
        #pragma unroll
        for (int mt = 0; mt < 4; mt++) {
            #pragma unroll
            for (int nt = 0; nt < 4; nt++) {
                int c = c0 + wc*64 + nt*16 + l15;
                int hh = c >> 6, dd = c & 63;
                #pragma unroll
                for (int reg = 0; reg < 4; reg++) {
                    int r = r0 + wr*64 + mt*16 + quad*4 + reg;
                    int bb = r >> 11, ss = r & (SEQ - 1);
                    float val = (acc[mt][nt][reg] + bias_v[nt]) * scale;
                    outp[(((size_t)(bb*NHEAD + hh)) * SEQ + ss) * HDIM + dd] = f2bf(val);
                }
            }
        }
    } else {
        #pragma unroll
        for (int mt = 0; mt < 4; mt++) {
            #pragma unroll
            for (int reg = 0; reg < 4; reg++) {
                int f = r0 + wr*64 + mt*16 + quad*4 + reg;   // feature
                int hh = f >> 6, dd = f & 63;
                float bfv = bias[f];
                #pragma unroll
                for (int nt = 0; nt < 4; nt++) {
                    int r = c0 + wc*64 + nt*16 + l15;        // seq row
                    int bb = r >> 11, ss = r & (SEQ - 1);
                    outp[(((size_t)(bb*NHEAD + hh)) * HDIM + dd) * SEQ + ss] =
                        f2bf(acc[mt][nt][reg] + bfv);
                }
            }
        }
    }
}

// ---------------------------------------------------------------------------
// Out projection, SPLIT-K (z = k-half): fp32 partials, no bias/residual
// (folded into LayerNorm). 512 blocks -> 2/CU.
// ---------------------------------------------------------------------------
__global__ __launch_bounds__(256) void oproj_gemm_kernel(
    const unsigned short* __restrict__ ws,
    float* __restrict__ p0, float* __restrict__ p1)
{
    __shared__ __align__(16) unsigned short As[8192];
    __shared__ __align__(16) unsigned short Bs[8192];
    const unsigned short* A = ws + OFF_XQ;      // ab lives where xq was
    const unsigned short* W = ws + OFF_WO;
    const int r0 = blockIdx.x * 128, c0 = blockIdx.y * 128;
    const int z = blockIdx.z;

    f32x4 acc[4][4] = {};
    gemm_body(A, W, r0, c0, z * 512, z * 512 + 512, As, Bs, acc);

    float* outp = z ? p1 : p0;
    const int lane = threadIdx.x & 63, wave = threadIdx.x >> 6;
    const int quad = lane >> 4, l15 = lane & 15;
    const int wr = wave >> 1, wc = wave & 1;
    #pragma unroll
    for (int mt = 0; mt < 4; mt++) {
        #pragma unroll
        for (int nt = 0; nt < 4; nt++) {
            int c = c0 + wc*64 + nt*16 + l15;
            #pragma unroll
            for (int reg = 0; reg < 4; reg++) {
                int r = r0 + wr*64 + mt*16 + quad*4 + reg;
                outp[(size_t)r * DMODEL + c] = acc[mt][nt][reg];
            }
        }
    }
}

// ---------------------------------------------------------------------------
// Flash attention, bf16 MFMA, static softmax. Block = 4 waves (256 thr),
// each wave owns 32 q-rows (two 16-row m-tiles) -> K/V LDS fragment reads
// amortize over 2x the q-rows vs 16-row waves (LDS pipe is the bottleneck).
// K/V^T chunks double-buffered via global_load_lds with XOR-rotated rows.
// ---------------------------------------------------------------------------
__global__ __launch_bounds__(256) void attn_mfma_kernel(
    const unsigned short* __restrict__ ws,
    const unsigned long long* __restrict__ cmask,
    const unsigned int* __restrict__ msum,
    unsigned short* __restrict__ ab)
{
    const int tid  = threadIdx.x;
    const int wave = tid >> 6, lane = tid & 63;
    const int quad = lane >> 4, l15 = lane & 15;
    const int h = blockIdx.y, b = blockIdx.z;
    const int qw = blockIdx.x * 128 + wave * 32;

    const char* qh = (const char*)(ws + OFF_QB + ((size_t)(b*NHEAD + h)) * SEQ * HDIM);
    const char* kh = (const char*)(ws + OFF_KB + ((size_t)(b*NHEAD + h)) * SEQ * HDIM);
    const char* vh = (const char*)(ws + OFF_VT + ((size_t)(b*NHEAD + h)) * SEQ * HDIM);

    __shared__ __align__(16) char Ks[2][8192];   // [key][d] rows, groups rotated
    __shared__ __align__(16) char Vs[2][8192];   // [d][key] rows, groups rotated
    __shared__ __align__(16) unsigned short Pl[4][32 * 72];
    unsigned short* Pw = Pl[wave];

    const unsigned int chunkflags = msum[(b << 4) | blockIdx.x];

    // staging: 256 threads x 16B = 4KB per call; row = tid>>3 (0..31, +32 for
    // the second call); phys group tid&7 holds logical ((tid&7) - row) & 7
    const int srow = tid >> 3;
    const int g0   = ((tid & 7) - srow) & 7;     // (row+32) gives same rotation

    #define STAGE(bf, k0)                                                          \
        do {                                                                       \
            gl_lds16(kh + (size_t)((k0) + srow) * 128 + g0 * 16,                   \
                     Ks[bf] + wave * 1024);                                        \
            gl_lds16(kh + (size_t)((k0) + srow + 32) * 128 + g0 * 16,              \
                     Ks[bf] + 4096 + wave * 1024);                                 \
            gl_lds16(vh + (size_t)srow * 4096 + (size_t)(k0) * 2 + g0 * 16,        \
                     Vs[bf] + wave * 1024);                                        \
            gl_lds16(vh + (size_t)(srow + 32) * 4096 + (size_t)(k0) * 2 + g0 * 16, \
                     Vs[bf] + 4096 + wave * 1024);                                 \
        } while (0)

    s16x8 qa[2][2];
    #pragma unroll
    for (int mt = 0; mt < 2; mt++)
        #pragma unroll
        for (int ks = 0; ks < 2; ks++)
            qa[mt][ks] = *(const s16x8*)(qh + (size_t)(qw + mt*16 + l15) * 128 + ks*64 + quad*16);

    s16x8 onesf;
    {
        short so = (short)0x3F80;  // bf16 1.0
        if (l15 == 0) onesf = (s16x8){so, so, so, so, so, so, so, so};
        else          onesf = (s16x8){0, 0, 0, 0, 0, 0, 0, 0};
    }

    f32x4 o[2][4], lsum[2];
    #pragma unroll
    for (int mt = 0; mt < 2; mt++) {
        lsum[mt] = (f32x4){0.f, 0.f, 0.f, 0.f};
        #pragma unroll
        for (int nt = 0; nt < 4; nt++) o[mt][nt] = (f32x4){0.f, 0.f, 0.f, 0.f};
    }

    STAGE(0, 0);
    int bf = 0;
    for (int k0 = 0; k0 < SEQ; k0 += 64) {
        __syncthreads();            // vmcnt(0): buf[bf] staged, buf[bf^1] free
        if (k0 + 64 < SEQ) STAGE(bf ^ 1, k0 + 64);

        const char* Kb = Ks[bf];
        const char* Vb = Vs[bf];
        // --- S = Q K^T (exp2-domain, pre-scaled); K-frags shared by 2 m-tiles ---
        f32x4 s[2][4];
        #pragma unroll
        for (int nt = 0; nt < 4; nt++) {
            int key = nt*16 + l15;
            s16x8 kf0 = *(const s16x8*)(Kb + key*128 + ((quad     + key) & 7) * 16);
            s16x8 kf1 = *(const s16x8*)(Kb + key*128 + ((4 + quad + key) & 7) * 16);
            #pragma unroll
            for (int mt = 0; mt < 2; mt++) {
                f32x4 z = {0.f, 0.f, 0.f, 0.f};
                s[mt][nt] = __builtin_amdgcn_mfma_f32_16x16x32_bf16(qa[mt][0], kf0, z, 0, 0, 0);
                s[mt][nt] = __builtin_amdgcn_mfma_f32_16x16x32_bf16(qa[mt][1], kf1, s[mt][nt], 0, 0, 0);
            }
        }
        // --- mask (wave-uniform skip when this chunk is all-ones) ---
        if (chunkflags & (1u << (k0 >> 6))) {
            const unsigned long long* cmp =
                cmask + ((size_t)b*32 + (k0 >> 6)) * SEQ + qw + quad*4;
            #pragma unroll
            for (int mt = 0; mt < 2; mt++)
                #pragma unroll
                for (int reg = 0; reg < 4; reg++) {
                    unsigned long long cm = cmp[mt*16 + reg];
                    if (cm != ~0ull) {
                        #pragma unroll
                        for (int nt = 0; nt < 4; nt++) {
                            int n = nt*16 + l15;
                            if (!((cm >> n) & 1)) s[mt][nt][reg] = -1e9f;
                        }
                    }
                }
        }
        // --- P = exp2(S) -> LDS (bf16 trunc; bias cancels in P/l) ---
        #pragma unroll
        for (int mt = 0; mt < 2; mt++)
            #pragma unroll
            for (int nt = 0; nt < 4; nt++)
                #pragma unroll
                for (int reg = 0; reg < 4; reg++) {
                    float pv = exp2f(s[mt][nt][reg]);
                    Pw[(mt*16 + quad*4 + reg) * 72 + nt*16 + l15] =
                        (unsigned short)(__builtin_bit_cast(unsigned int, pv) >> 16);
                }
        // --- O += P @ V ; l += P @ 1 ; V-frags shared by 2 m-tiles ---
        #pragma unroll
        for (int ks = 0; ks < 2; ks++) {
            s16x8 pa[2];
            #pragma unroll
            for (int mt = 0; mt < 2; mt++) {
                pa[mt] = *(const s16x8*)((const char*)Pw + (mt*16 + l15) * 144 + ks*64 + quad*16);
                lsum[mt] = __builtin_amdgcn_mfma_f32_16x16x32_bf16(pa[mt], onesf, lsum[mt], 0, 0, 0);
            }
            #pragma unroll
            for (int nt = 0; nt < 4; nt++) {
                int d = nt*16 + l15;
                s16x8 vf = *(const s16x8*)(Vb + d*128 + ((ks*4 + quad + d) & 7) * 16);
                #pragma unroll
                for (int mt = 0; mt < 2; mt++)
                    o[mt][nt] = __builtin_amdgcn_mfma_f32_16x16x32_bf16(pa[mt], vf, o[mt][nt], 0, 0, 0);
            }
        }
        bf ^= 1;
    }
    #undef STAGE
    // --- epilogue: O / l -> ab [B,S,DMODEL] bf16 (l at lanes l15==0) ---
    #pragma unroll
    for (int mt = 0; mt < 2; mt++)
        #pragma unroll
        for (int reg = 0; reg < 4; reg++) {
            float lv = __shfl(lsum[mt][reg], lane & 48);
            float inv = 1.f / lv;
            int sg = qw + mt*16 + quad*4 + reg;
            #pragma unroll
            for (int nt = 0; nt < 4; nt++) {
                size_t idx = ((size_t)b * SEQ + sg) * DMODEL + h*HDIM + nt*16 + l15;
                ab[idx] = f2bf(o[mt][nt][reg] * inv);
            }
        }
}

// ---------------------------------------------------------------------------
// LayerNorm fused with split-K reduction + bias + residual:
// x = p0 + p1 + bo + resid, then gamma*(x-mean)/(std+eps)+beta (ddof=1)
// ---------------------------------------------------------------------------
__global__ __launch_bounds__(256) void ln_kernel(
    const float* __restrict__ p0, const float* __restrict__ p1,
    const float* __restrict__ resid, const float* __restrict__ bo,
    const float* __restrict__ gamma, const float* __restrict__ beta,
    float* __restrict__ out)
{
    const int row = blockIdx.x;
    const int tid = threadIdx.x;
    const size_t i = (size_t)row * DMODEL + tid * 4;
    float4 a  = *(const float4*)&p0[i];
    float4 b2 = *(const float4*)&p1[i];
    float4 r  = *(const float4*)&resid[i];
    float4 bb = *(const float4*)&bo[tid * 4];
    float4 vals;
    vals.x = a.x + b2.x + r.x + bb.x;
    vals.y = a.y + b2.y + r.y + bb.y;
    vals.z = a.z + b2.z + r.z + bb.z;
    vals.w = a.w + b2.w + r.w + bb.w;
    float s  = vals.x + vals.y + vals.z + vals.w;
    float ss = vals.x*vals.x + vals.y*vals.y + vals.z*vals.z + vals.w*vals.w;
    #pragma unroll
    for (int off = 32; off > 0; off >>= 1) {
        s  += __shfl_down(s, off);
        ss += __shfl_down(ss, off);
    }
    __shared__ float sbuf[4], ssbuf[4];
    __shared__ float mean_s, inv_s;
    if ((tid & 63) == 0) { sbuf[tid >> 6] = s; ssbuf[tid >> 6] = ss; }
    __syncthreads();
    if (tid == 0) {
        float S1 = 0.f, S2 = 0.f;
        #pragma unroll
        for (int i2 = 0; i2 < 4; i2++) { S1 += sbuf[i2]; S2 += ssbuf[i2]; }
        float mean = S1 * (1.0f / DMODEL);
        float var  = (S2 - (float)DMODEL * mean * mean) * (1.0f / (DMODEL - 1));
        float sd   = sqrtf(fmaxf(var, 0.f));
        mean_s = mean;
        inv_s  = 1.f / (sd + EPS);
    }
    __syncthreads();
    float4 g  = *(const float4*)&gamma[tid * 4];
    float4 bt = *(const float4*)&beta[tid * 4];
    float4 o;
    o.x = g.x * (vals.x - mean_s) * inv_s + bt.x;
    o.y = g.y * (vals.y - mean_s) * inv_s + bt.y;
    o.z = g.z * (vals.z - mean_s) * inv_s + bt.z;
    o.w = g.w * (vals.w - mean_s) * inv_s + bt.w;
    *(float4*)&out[i] = o;
}

extern "C" void kernel_launch(void* const* d_in, const int* in_sizes, int n_in,
                              void* d_out, int out_size, void* d_ws, size_t ws_size,
                              hipStream_t stream) {
    const float* query = (const float*)d_in[0];
    const float* key   = (const float*)d_in[1];
    const float* value = (const float*)d_in[2];
    const int*   mask  = (const int*)d_in[3];
    const float* Wq = (const float*)d_in[4];  const float* bq = (const float*)d_in[5];
    const float* Wk = (const float*)d_in[6];  const float* bk = (const float*)d_in[7];
    const float* Wv = (const float*)d_in[8];  const float* bv = (const float*)d_in[9];
    const float* Wo = (const float*)d_in[10]; const float* bo = (const float*)d_in[11];
    const float* gamma = (const float*)d_in[12];
    const float* beta  = (const float*)d_in[13];
    float* out = (float*)d_out;

    unsigned short* ws = (unsigned short*)d_ws;
    unsigned long long* cmask = (unsigned long long*)(ws + OFF_CM);
    unsigned int* msum = (unsigned int*)(ws + OFF_MS);
    float* p0 = (float*)(ws + OFF_XK);   // 16 MB: xk+xv region (free post-qkv)
    float* p1 = (float*)(ws + OFF_QB);   // 16 MB: qb+kb region (free post-attn)

    hipMemsetAsync(msum, 0, 128, stream);
    conv_all_kernel<<<16896, 256, 0, stream>>>(query, key, value, Wq, Wk, Wv, Wo,
                                               ws, mask, cmask, msum);
    qkv_gemm_kernel<<<dim3(32, 8, 3), 256, 0, stream>>>(ws, bq, bk, bv);
    attn_mfma_kernel<<<dim3(SEQ/128, NHEAD, BATCH), 256, 0, stream>>>(ws, cmask, msum, ws + OFF_XQ);
    oproj_gemm_kernel<<<dim3(32, 8, 2), 256, 0, stream>>>(ws, p0, p1);
    ln_kernel<<<NROWS, 256, 0, stream>>>(p0, p1, query, bo, gamma, beta, out);
}

// Round 8
// 309.071 us; speedup vs baseline: 1.0160x; 1.0160x over previous
//
#include <hip/hip_runtime.h>
#include <hip/hip_bf16.h>
#include <math.h>
#include <stdint.h>

#define BATCH 2
#define SEQ   2048
#define DMODEL 1024
#define NHEAD 16
#define HDIM  64
#define NROWS (BATCH*SEQ)          // 4096
#define EPS   1e-6f
#define QSCALE 0.1803368801111204f // 0.125 * log2(e): softmax in exp2 domain

typedef float f32x4 __attribute__((ext_vector_type(4)));
typedef short s16x8 __attribute__((ext_vector_type(8)));

// ws layout (ushort units):
//  xq @ 0            (4194304)   -> reused as ab (attention out) after projections
//  xk @ 4194304
//  xv @ 8388608
//  wq @ 12582912     (1048576 each)
//  wk @ 13631488
//  wv @ 14680064
//  wo @ 15728640
//  qb @ 16777216     [B,H,S,64] bf16, pre-scaled by QSCALE
//  kb @ 20971520     [B,H,S,64] bf16
//  vt @ 25165824     [B,H,64,S] bf16 (V transposed)
//  cmask @ 29360128  (1 MB): [B][32 kblocks][S] uint64 bitmask
//  msum  @ 29884416  (128 B): [B][16 qb128] uint32, bit kb = "has masked"
#define OFF_XQ 0
#define OFF_XK 4194304
#define OFF_XV 8388608
#define OFF_WQ 12582912
#define OFF_WK 13631488
#define OFF_WV 14680064
#define OFF_WO 15728640
#define OFF_QB 16777216
#define OFF_KB 20971520
#define OFF_VT 25165824
#define OFF_CM 29360128
#define OFF_MS 29884416

__device__ __forceinline__ unsigned short f2bf(float x) {
    unsigned int u = __builtin_bit_cast(unsigned int, x);
    u += 0x7fff + ((u >> 16) & 1);            // round-to-nearest-even
    return (unsigned short)(u >> 16);
}

__device__ __forceinline__ void gl_lds16(const void* g, void* l) {
    __builtin_amdgcn_global_load_lds(
        (const __attribute__((address_space(1))) unsigned int*)g,
        (__attribute__((address_space(3))) unsigned int*)(unsigned int)(unsigned long long)l,
        16, 0, 0);
}

// ---------------------------------------------------------------------------
// fused fp32 -> bf16 convert of q/k/v + 4 weights, PLUS mask compression
// (blocks >= 16384 do the mask; msum zero-init via hipMemsetAsync before)
// ---------------------------------------------------------------------------
__global__ __launch_bounds__(256) void conv_all_kernel(
    const float* __restrict__ q, const float* __restrict__ k, const float* __restrict__ v,
    const float* __restrict__ wq, const float* __restrict__ wk, const float* __restrict__ wv,
    const float* __restrict__ wo, unsigned short* __restrict__ ws,
    const int* __restrict__ mask, unsigned long long* __restrict__ cm,
    unsigned int* __restrict__ msum)
{
    if (blockIdx.x >= 16384) {
        int t = (blockIdx.x - 16384) * 256 + threadIdx.x;  // [0, 2*32*2048)
        int s  = t & 2047;
        int kb = (t >> 11) & 31;
        int b  = t >> 16;
        const int* mp = mask + ((size_t)b * SEQ + s) * SEQ + kb * 64;
        unsigned long long bits = 0;
        #pragma unroll
        for (int i = 0; i < 16; i++) {
            int4 m4 = *(const int4*)&mp[i * 4];
            unsigned long long nib =
                (unsigned long long)((m4.x != 0) | ((m4.y != 0) << 1) |
                                     ((m4.z != 0) << 2) | ((m4.w != 0) << 3));
            bits |= nib << (i * 4);
        }
        cm[((size_t)b * 32 + kb) * SEQ + s] = bits;
        if (bits != ~0ull)
            atomicOr(&msum[(b << 4) | (s >> 7)], 1u << kb);
        return;
    }
    size_t t = ((size_t)blockIdx.x * 256 + threadIdx.x) * 4;
    const float* src; unsigned short* dst; size_t off;
    if (t < 4194304)       { src = q;  dst = ws + OFF_XQ; off = t; }
    else if (t < 8388608)  { src = k;  dst = ws + OFF_XK; off = t - 4194304; }
    else if (t < 12582912) { src = v;  dst = ws + OFF_XV; off = t - 8388608; }
    else if (t < 13631488) { src = wq; dst = ws + OFF_WQ; off = t - 12582912; }
    else if (t < 14680064) { src = wk; dst = ws + OFF_WK; off = t - 13631488; }
    else if (t < 15728640) { src = wv; dst = ws + OFF_WV; off = t - 14680064; }
    else                   { src = wo; dst = ws + OFF_WO; off = t - 15728640; }
    float4 x = *(const float4*)&src[off];
    ushort4 o;
    o.x = f2bf(x.x); o.y = f2bf(x.y); o.z = f2bf(x.z); o.w = f2bf(x.w);
    *(ushort4*)&dst[off] = o;
}

// ---------------------------------------------------------------------------
// Shared GEMM tile body: C[128x128] += A[r0..] * W[c0..]^T, bf16 MFMA.
// A,W row-major bf16 with K stride 1024. Per-wave 64x64 = 4x4 C-frags.
// ---------------------------------------------------------------------------
__device__ __forceinline__ void gemm_body(
    const unsigned short* A, const unsigned short* W, int r0, int c0,
    unsigned short* As, unsigned short* Bs, f32x4 acc[4][4])
{
    const int tid  = threadIdx.x;
    const int wave = tid >> 6, lane = tid & 63;
    const int quad = lane >> 4, l15 = lane & 15;
    const int wr = wave >> 1, wc = wave & 1;
    for (int k0 = 0; k0 < DMODEL; k0 += 64) {
        __syncthreads();
        #pragma unroll
        for (int r = 0; r < 4; r++) {
            int f = r * 4096 + tid * 16;      // byte offset in 16KB tile
            int row = f >> 7, cb = f & 127;
            gl_lds16((const char*)A + (size_t)(r0 + row) * 2048 + k0 * 2 + cb,
                     (char*)As + r * 4096 + wave * 1024);
            gl_lds16((const char*)W + (size_t)(c0 + row) * 2048 + k0 * 2 + cb,
                     (char*)Bs + r * 4096 + wave * 1024);
        }
        __syncthreads();
        #pragma unroll
        for (int ks = 0; ks < 2; ks++) {
            s16x8 a[4], b[4];
            #pragma unroll
            for (int mt = 0; mt < 4; mt++)
                a[mt] = *(const s16x8*)((const char*)As + (wr*64 + mt*16 + l15) * 128 + ks*64 + quad*16);
            #pragma unroll
            for (int nt = 0; nt < 4; nt++)
                b[nt] = *(const s16x8*)((const char*)Bs + (wc*64 + nt*16 + l15) * 128 + ks*64 + quad*16);
            #pragma unroll
            for (int mt = 0; mt < 4; mt++)
                #pragma unroll
                for (int nt = 0; nt < 4; nt++)
                    acc[mt][nt] = __builtin_amdgcn_mfma_f32_16x16x32_bf16(a[mt], b[nt], acc[mt][nt], 0, 0, 0);
        }
    }
}

// ---------------------------------------------------------------------------
// QKV projections, 1-D grid 768 with XCD-aware decode: all 8 column-tiles of
// one row-tile get ids congruent mod 8 (stride 96) -> same XCD -> the 256 KB
// streamed A row-tile stays L2-resident across its 8 re-reads.
// z=0 -> q (scaled, [B,H,S,d]), z=1 -> k, z=2 -> V^T = Wv * X^T (operand
// swap, coalesced [B,H,d,S] stores).
// ---------------------------------------------------------------------------
__global__ __launch_bounds__(256) void qkv_gemm_kernel(
    unsigned short* __restrict__ ws,
    const float* __restrict__ bq, const float* __restrict__ bk, const float* __restrict__ bv)
{
    __shared__ __align__(16) unsigned short As[8192];
    __shared__ __align__(16) unsigned short Bs[8192];
    const int id = blockIdx.x;
    const int col8  = id / 96;        // 0..7  column-tile
    const int rz    = id % 96;
    const int z     = rz >> 5;        // 0..2
    const int row32 = rz & 31;        // 0..31 row-tile
    const unsigned short *A, *W;
    int r0, c0;
    if (z != 2) {
        A = ws + (size_t)z * 4194304;            // xq/xk (streamed, 8 MB)
        W = ws + OFF_WQ + (size_t)z * 1048576;
        r0 = row32 * 128; c0 = col8 * 128;
    } else {
        A = ws + OFF_WV;                         // rows = output features
        W = ws + OFF_XV;                         // streamed seq rows (8 MB)
        r0 = col8 * 128;  c0 = row32 * 128;
    }
    const float* bias = (z == 0) ? bq : (z == 1 ? bk : bv);
    unsigned short* outp = ws + OFF_QB + (size_t)z * 4194304;      // qb/kb/vt
    const float scale = (z == 0) ? QSCALE : 1.0f;

    f32x4 acc[4][4] = {};
    gemm_body(A, W, r0, c0, As, Bs, acc);

    const int lane = threadIdx.x & 63, wave = threadIdx.x >> 6;
    const int quad = lane >> 4, l15 = lane & 15;
    const int wr = wave >> 1, wc = wave & 1;
    if (z != 2) {
        float bias_v[4];
        #pragma unroll
        for (int nt = 0; nt < 4; nt++) bias_v[nt] = bias[c0 + wc*64 + nt*16 + l15];
        #pragma unroll
        for (int mt = 0; mt < 4; mt++) {
            #pragma unroll
            for (int nt = 0; nt < 4; nt++) {
                int c = c0 + wc*64 + nt*16 + l15;
                int hh = c >> 6, dd = c & 63;
                #pragma unroll
                for (int reg = 0; reg < 4; reg++) {
                    int r = r0 + wr*64 + mt*16 + quad*4 + reg;
                    int bb = r >> 11, ss = r & (SEQ - 1);
                    float val = (acc[mt][nt][reg] + bias_v[nt]) * scale;
                    outp[(((size_t)(bb*NHEAD + hh)) * SEQ + ss) * HDIM + dd] = f2bf(val);
                }
            }
        }
    } else {
        #pragma unroll
        for (int mt = 0; mt < 4; mt++) {
            #pragma unroll
            for (int reg = 0; reg < 4; reg++) {
                int f = r0 + wr*64 + mt*16 + quad*4 + reg;   // feature
                int hh = f >> 6, dd = f & 63;
                float bfv = bias[f];
                #pragma unroll
                for (int nt = 0; nt < 4; nt++) {
                    int r = c0 + wc*64 + nt*16 + l15;        // seq row
                    int bb = r >> 11, ss = r & (SEQ - 1);
                    outp[(((size_t)(bb*NHEAD + hh)) * HDIM + dd) * SEQ + ss] =
                        f2bf(acc[mt][nt][reg] + bfv);
                }
            }
        }
    }
}

// ---------------------------------------------------------------------------
// Out projection: out = ab @ Wo^T + bo + residual (fp32 out).
// 1-D grid 256, XCD-aware decode (stride-32 ids share a row-tile -> same XCD).
// ---------------------------------------------------------------------------
__global__ __launch_bounds__(256) void oproj_gemm_kernel(
    const unsigned short* __restrict__ ws, const float* __restrict__ bo,
    const float* __restrict__ resid, float* __restrict__ outf)
{
    __shared__ __align__(16) unsigned short As[8192];
    __shared__ __align__(16) unsigned short Bs[8192];
    const unsigned short* A = ws + OFF_XQ;      // ab lives where xq was
    const unsigned short* W = ws + OFF_WO;
    const int id = blockIdx.x;
    const int r0 = (id & 31) * 128, c0 = (id >> 5) * 128;

    f32x4 acc[4][4] = {};
    gemm_body(A, W, r0, c0, (unsigned short*)As, (unsigned short*)Bs, acc);

    const int lane = threadIdx.x & 63, wave = threadIdx.x >> 6;
    const int quad = lane >> 4, l15 = lane & 15;
    const int wr = wave >> 1, wc = wave & 1;
    #pragma unroll
    for (int mt = 0; mt < 4; mt++) {
        #pragma unroll
        for (int nt = 0; nt < 4; nt++) {
            int c = c0 + wc*64 + nt*16 + l15;
            float bv = bo[c];
            #pragma unroll
            for (int reg = 0; reg < 4; reg++) {
                int r = r0 + wr*64 + mt*16 + quad*4 + reg;
                size_t idx = (size_t)r * DMODEL + c;
                outf[idx] = acc[mt][nt][reg] + bv + resid[idx];
            }
        }
    }
}

// ---------------------------------------------------------------------------
// Flash attention, bf16 MFMA, static softmax (R5 version, proven stable).
// Block = 8 waves (512 thr), 128 q-rows; wave owns 16 q-rows. K/V^T 64-key
// chunks staged to LDS (global_load_lds, XOR-rotated rows, double-buffered).
// l via MFMA ones-column; P packed by truncation (bias cancels in P/l);
// per-(b,qb128) chunk summary -> zero mask loads when chunks are all-ones.
// ---------------------------------------------------------------------------
__global__ __launch_bounds__(512) void attn_mfma_kernel(
    const unsigned short* __restrict__ ws,
    const unsigned long long* __restrict__ cmask,
    const unsigned int* __restrict__ msum,
    unsigned short* __restrict__ ab)
{
    const int tid  = threadIdx.x;
    const int wave = tid >> 6, lane = tid & 63;
    const int quad = lane >> 4, l15 = lane & 15;
    const int h = blockIdx.y, b = blockIdx.z;
    const int qw = blockIdx.x * 128 + wave * 16;

    const char* qh = (const char*)(ws + OFF_QB + ((size_t)(b*NHEAD + h)) * SEQ * HDIM);
    const char* kh = (const char*)(ws + OFF_KB + ((size_t)(b*NHEAD + h)) * SEQ * HDIM);
    const char* vh = (const char*)(ws + OFF_VT + ((size_t)(b*NHEAD + h)) * SEQ * HDIM);

    __shared__ __align__(16) char Ks[2][8192];   // [key][d] rows, groups rotated
    __shared__ __align__(16) char Vs[2][8192];   // [d][key] rows, groups rotated
    __shared__ __align__(16) unsigned short Pl[8][16 * 72];
    unsigned short* Pw = Pl[wave];

    const unsigned int chunkflags = msum[(b << 4) | blockIdx.x];

    // staging: 512 threads x 16B = one 8KB buffer per call; row = tid>>3,
    // phys group tid&7 holds logical group ((tid&7) - row) & 7 (XOR-rotate)
    const int srow = tid >> 3;
    const int sgrp = ((tid & 7) - srow) & 7;

    #define STAGE(bf, k0)                                                       \
        do {                                                                    \
            gl_lds16(kh + (size_t)((k0) + srow) * 128 + sgrp * 16,              \
                     Ks[bf] + wave * 1024);                                     \
            gl_lds16(vh + (size_t)srow * 4096 + (size_t)(k0) * 2 + sgrp * 16,   \
                     Vs[bf] + wave * 1024);                                     \
        } while (0)

    s16x8 qa[2];
    #pragma unroll
    for (int ks = 0; ks < 2; ks++)
        qa[ks] = *(const s16x8*)(qh + (size_t)(qw + l15) * 128 + ks*64 + quad*16);

    s16x8 onesf;
    {
        short so = (short)0x3F80;  // bf16 1.0
        if (l15 == 0) onesf = (s16x8){so, so, so, so, so, so, so, so};
        else          onesf = (s16x8){0, 0, 0, 0, 0, 0, 0, 0};
    }

    f32x4 o[4], lsum = {0.f, 0.f, 0.f, 0.f};
    #pragma unroll
    for (int nt = 0; nt < 4; nt++) o[nt] = (f32x4){0.f, 0.f, 0.f, 0.f};

    STAGE(0, 0);
    int bf = 0;
    for (int k0 = 0; k0 < SEQ; k0 += 64) {
        __syncthreads();            // vmcnt(0): buf[bf] staged, buf[bf^1] free
        // prefetch next chunk into the other buffer
        if (k0 + 64 < SEQ) STAGE(bf ^ 1, k0 + 64);

        const char* Kb = Ks[bf];
        const char* Vb = Vs[bf];
        // --- S = Q K^T (exp2-domain, pre-scaled) ---
        f32x4 s[4];
        #pragma unroll
        for (int nt = 0; nt < 4; nt++) {
            int key = nt*16 + l15;
            s16x8 kf0 = *(const s16x8*)(Kb + key*128 + ((quad     + key) & 7) * 16);
            s16x8 kf1 = *(const s16x8*)(Kb + key*128 + ((4 + quad + key) & 7) * 16);
            f32x4 z = {0.f, 0.f, 0.f, 0.f};
            s[nt] = __builtin_amdgcn_mfma_f32_16x16x32_bf16(qa[0], kf0, z, 0, 0, 0);
            s[nt] = __builtin_amdgcn_mfma_f32_16x16x32_bf16(qa[1], kf1, s[nt], 0, 0, 0);
        }
        // --- mask (wave-uniform skip when this chunk is all-ones) ---
        if (chunkflags & (1u << (k0 >> 6))) {
            const unsigned long long* cmp =
                cmask + ((size_t)b*32 + (k0 >> 6)) * SEQ + qw + quad*4;
            #pragma unroll
            for (int reg = 0; reg < 4; reg++) {
                unsigned long long cm = cmp[reg];
                if (cm != ~0ull) {
                    #pragma unroll
                    for (int nt = 0; nt < 4; nt++) {
                        int n = nt*16 + l15;
                        if (!((cm >> n) & 1)) s[nt][reg] = -1e9f;
                    }
                }
            }
        }
        // --- P = exp2(S) -> LDS (bf16 trunc; bias cancels in P/l) ---
        #pragma unroll
        for (int nt = 0; nt < 4; nt++)
            #pragma unroll
            for (int reg = 0; reg < 4; reg++) {
                float pv = exp2f(s[nt][reg]);
                Pw[(quad*4 + reg) * 72 + nt*16 + l15] =
                    (unsigned short)(__builtin_bit_cast(unsigned int, pv) >> 16);
            }
        // --- O += P @ V ; l += P @ 1 (ones-column MFMA) ---
        #pragma unroll
        for (int ks = 0; ks < 2; ks++) {
            s16x8 pa = *(const s16x8*)((const char*)Pw + l15 * 144 + ks*64 + quad*16);
            lsum = __builtin_amdgcn_mfma_f32_16x16x32_bf16(pa, onesf, lsum, 0, 0, 0);
            #pragma unroll
            for (int nt = 0; nt < 4; nt++) {
                int d = nt*16 + l15;
                s16x8 vf = *(const s16x8*)(Vb + d*128 + ((ks*4 + quad + d) & 7) * 16);
                o[nt] = __builtin_amdgcn_mfma_f32_16x16x32_bf16(pa, vf, o[nt], 0, 0, 0);
            }
        }
        bf ^= 1;
    }
    #undef STAGE
    // --- epilogue: O / l -> ab [B,S,DMODEL] bf16 (l at lanes l15==0) ---
    #pragma unroll
    for (int reg = 0; reg < 4; reg++) {
        float lv = __shfl(lsum[reg], lane & 48);
        float inv = 1.f / lv;
        int sg = qw + quad*4 + reg;
        #pragma unroll
        for (int nt = 0; nt < 4; nt++) {
            size_t idx = ((size_t)b * SEQ + sg) * DMODEL + h*HDIM + nt*16 + l15;
            ab[idx] = f2bf(o[nt][reg] * inv);
        }
    }
}

// ---------------------------------------------------------------------------
// LayerNorm (unbiased std, (std+eps) denominator), in-place on fp32 rows
// ---------------------------------------------------------------------------
__global__ __launch_bounds__(256) void ln_kernel(
    float* __restrict__ x, const float* __restrict__ gamma,
    const float* __restrict__ beta)
{
    const int row = blockIdx.x;
    const int tid = threadIdx.x;
    float4 vals = *(const float4*)&x[(size_t)row * DMODEL + tid * 4];
    float s  = vals.x + vals.y + vals.z + vals.w;
    float ss = vals.x*vals.x + vals.y*vals.y + vals.z*vals.z + vals.w*vals.w;
    #pragma unroll
    for (int off = 32; off > 0; off >>= 1) {
        s  += __shfl_down(s, off);
        ss += __shfl_down(ss, off);
    }
    __shared__ float sbuf[4], ssbuf[4];
    __shared__ float mean_s, inv_s;
    if ((tid & 63) == 0) { sbuf[tid >> 6] = s; ssbuf[tid >> 6] = ss; }
    __syncthreads();
    if (tid == 0) {
        float S1 = 0.f, S2 = 0.f;
        #pragma unroll
        for (int i = 0; i < 4; i++) { S1 += sbuf[i]; S2 += ssbuf[i]; }
        float mean = S1 * (1.0f / DMODEL);
        float var  = (S2 - (float)DMODEL * mean * mean) * (1.0f / (DMODEL - 1));
        float sd   = sqrtf(fmaxf(var, 0.f));
        mean_s = mean;
        inv_s  = 1.f / (sd + EPS);
    }
    __syncthreads();
    float4 g  = *(const float4*)&gamma[tid * 4];
    float4 bt = *(const float4*)&beta[tid * 4];
    float4 o;
    o.x = g.x * (vals.x - mean_s) * inv_s + bt.x;
    o.y = g.y * (vals.y - mean_s) * inv_s + bt.y;
    o.z = g.z * (vals.z - mean_s) * inv_s + bt.z;
    o.w = g.w * (vals.w - mean_s) * inv_s + bt.w;
    *(float4*)&x[(size_t)row * DMODEL + tid * 4] = o;
}

extern "C" void kernel_launch(void* const* d_in, const int* in_sizes, int n_in,
                              void* d_out, int out_size, void* d_ws, size_t ws_size,
                              hipStream_t stream) {
    const float* query = (const float*)d_in[0];
    const float* key   = (const float*)d_in[1];
    const float* value = (const float*)d_in[2];
    const int*   mask  = (const int*)d_in[3];
    const float* Wq = (const float*)d_in[4];  const float* bq = (const float*)d_in[5];
    const float* Wk = (const float*)d_in[6];  const float* bk = (const float*)d_in[7];
    const float* Wv = (const float*)d_in[8];  const float* bv = (const float*)d_in[9];
    const float* Wo = (const float*)d_in[10]; const float* bo = (const float*)d_in[11];
    const float* gamma = (const float*)d_in[12];
    const float* beta  = (const float*)d_in[13];
    float* out = (float*)d_out;

    unsigned short* ws = (unsigned short*)d_ws;
    unsigned long long* cmask = (unsigned long long*)(ws + OFF_CM);
    unsigned int* msum = (unsigned int*)(ws + OFF_MS);

    hipMemsetAsync(msum, 0, 128, stream);
    conv_all_kernel<<<16896, 256, 0, stream>>>(query, key, value, Wq, Wk, Wv, Wo,
                                               ws, mask, cmask, msum);
    qkv_gemm_kernel<<<768, 256, 0, stream>>>(ws, bq, bk, bv);
    attn_mfma_kernel<<<dim3(SEQ/128, NHEAD, BATCH), 512, 0, stream>>>(ws, cmask, msum, ws + OFF_XQ);
    oproj_gemm_kernel<<<256, 256, 0, stream>>>(ws, bo, query, out);
    ln_kernel<<<NROWS, 256, 0, stream>>>(out, gamma, beta);
}

// Round 9
// 280.140 us; speedup vs baseline: 1.1209x; 1.1033x over previous
//
#include <hip/hip_runtime.h>
#include <hip/hip_bf16.h>
#include <math.h>
#include <stdint.h>

#define BATCH 2
#define SEQ   2048
#define DMODEL 1024
#define NHEAD 16
#define HDIM  64
#define NROWS (BATCH*SEQ)          // 4096
#define EPS   1e-6f
#define QSCALE 0.1803368801111204f // 0.125 * log2(e): softmax in exp2 domain

typedef float f32x4 __attribute__((ext_vector_type(4)));
typedef short s16x8 __attribute__((ext_vector_type(8)));

// ws layout (ushort units):
//  xq @ 0            (4194304)   -> reused as ab (attention out) after projections
//  xk @ 4194304
//  xv @ 8388608
//  wq @ 12582912     (1048576 each)
//  wk @ 13631488
//  wv @ 14680064
//  wo @ 15728640
//  qb @ 16777216     [B,H,S,64] bf16, pre-scaled by QSCALE
//  kb @ 20971520     [B,H,S,64] bf16
//  vt @ 25165824     [B,H,64,S] bf16 (V transposed)
//  cmask @ 29360128  (1 MB): [B][32 kblocks][S] uint64 bitmask
//  msum  @ 29884416  (128 B): [B][16 qb128] uint32, bit kb = "has masked"
#define OFF_XQ 0
#define OFF_XK 4194304
#define OFF_XV 8388608
#define OFF_WQ 12582912
#define OFF_WK 13631488
#define OFF_WV 14680064
#define OFF_WO 15728640
#define OFF_QB 16777216
#define OFF_KB 20971520
#define OFF_VT 25165824
#define OFF_CM 29360128
#define OFF_MS 29884416

__device__ __forceinline__ unsigned short f2bf(float x) {
    unsigned int u = __builtin_bit_cast(unsigned int, x);
    u += 0x7fff + ((u >> 16) & 1);            // round-to-nearest-even
    return (unsigned short)(u >> 16);
}

__device__ __forceinline__ void gl_lds16(const void* g, void* l) {
    __builtin_amdgcn_global_load_lds(
        (const __attribute__((address_space(1))) unsigned int*)g,
        (__attribute__((address_space(3))) unsigned int*)(unsigned int)(unsigned long long)l,
        16, 0, 0);
}

// ---------------------------------------------------------------------------
// fused fp32 -> bf16 convert of query/key/value + 4 weight matrices
// (also zero-inits the mask summary words for the following dispatch)
// ---------------------------------------------------------------------------
__global__ __launch_bounds__(256) void conv_all_kernel(
    const float* __restrict__ q, const float* __restrict__ k, const float* __restrict__ v,
    const float* __restrict__ wq, const float* __restrict__ wk, const float* __restrict__ wv,
    const float* __restrict__ wo, unsigned short* __restrict__ ws)
{
    if (blockIdx.x == 0 && threadIdx.x < 32)
        ((unsigned int*)(ws + OFF_MS))[threadIdx.x] = 0;
    size_t t = ((size_t)blockIdx.x * 256 + threadIdx.x) * 4;
    const float* src; unsigned short* dst; size_t off;
    if (t < 4194304)       { src = q;  dst = ws + OFF_XQ; off = t; }
    else if (t < 8388608)  { src = k;  dst = ws + OFF_XK; off = t - 4194304; }
    else if (t < 12582912) { src = v;  dst = ws + OFF_XV; off = t - 8388608; }
    else if (t < 13631488) { src = wq; dst = ws + OFF_WQ; off = t - 12582912; }
    else if (t < 14680064) { src = wk; dst = ws + OFF_WK; off = t - 13631488; }
    else if (t < 15728640) { src = wv; dst = ws + OFF_WV; off = t - 14680064; }
    else                   { src = wo; dst = ws + OFF_WO; off = t - 15728640; }
    float4 x = *(const float4*)&src[off];
    ushort4 o;
    o.x = f2bf(x.x); o.y = f2bf(x.y); o.z = f2bf(x.z); o.w = f2bf(x.w);
    *(ushort4*)&dst[off] = o;
}

// ---------------------------------------------------------------------------
// mask -> per-(b, kblock, s) 64-bit bitmask + per-(b, qb128) chunk summary
// ---------------------------------------------------------------------------
__global__ __launch_bounds__(256) void mask_compress_kernel(
    const int* __restrict__ mask, unsigned long long* __restrict__ cm,
    unsigned int* __restrict__ msum)
{
    int t = blockIdx.x * 256 + threadIdx.x;  // [0, 2*32*2048)
    int s  = t & 2047;
    int kb = (t >> 11) & 31;
    int b  = t >> 16;
    const int* mp = mask + ((size_t)b * SEQ + s) * SEQ + kb * 64;
    unsigned long long bits = 0;
    #pragma unroll
    for (int i = 0; i < 16; i++) {
        int4 m4 = *(const int4*)&mp[i * 4];
        unsigned long long nib =
            (unsigned long long)((m4.x != 0) | ((m4.y != 0) << 1) |
                                 ((m4.z != 0) << 2) | ((m4.w != 0) << 3));
        bits |= nib << (i * 4);
    }
    cm[((size_t)b * 32 + kb) * SEQ + s] = bits;
    if (bits != ~0ull)
        atomicOr(&msum[(b << 4) | (s >> 7)], 1u << kb);
}

// ---------------------------------------------------------------------------
// Shared GEMM tile body: C[128x128] += A[r0..] * W[c0..]^T, bf16 MFMA.
// A,W row-major bf16 with K stride 1024. Per-wave 64x64 = 4x4 C-frags.
// LDS rows (128 B) are XOR-ROTATED by row index: phys 16B-group p of row r
// holds logical group (p - r) & 7 (rotation folded into the GLOBAL source
// address, since global_load_lds's LDS side is fixed base + lane*16).
// Fragment reads use group ((ks*4+quad) + row) & 7 -> consecutive rows hit
// rotated bank groups (2-way aliasing = free) instead of 16 rows on one
// bank group (the 9.4e6-conflict hotspot measured in R8).
// ---------------------------------------------------------------------------
__device__ __forceinline__ void gemm_body(
    const unsigned short* A, const unsigned short* W, int r0, int c0,
    unsigned short* As, unsigned short* Bs, f32x4 acc[4][4])
{
    const int tid  = threadIdx.x;
    const int wave = tid >> 6, lane = tid & 63;
    const int quad = lane >> 4, l15 = lane & 15;
    const int wr = wave >> 1, wc = wave & 1;
    for (int k0 = 0; k0 < DMODEL; k0 += 64) {
        __syncthreads();
        #pragma unroll
        for (int r = 0; r < 4; r++) {
            int f   = r * 4096 + tid * 16;    // byte offset in 16KB tile
            int row = f >> 7;                 // tile row 0..127
            int g   = (((f >> 4) & 7) - row) & 7;   // logical group at this slot
            gl_lds16((const char*)A + (size_t)(r0 + row) * 2048 + k0 * 2 + g * 16,
                     (char*)As + r * 4096 + wave * 1024);
            gl_lds16((const char*)W + (size_t)(c0 + row) * 2048 + k0 * 2 + g * 16,
                     (char*)Bs + r * 4096 + wave * 1024);
        }
        __syncthreads();
        #pragma unroll
        for (int ks = 0; ks < 2; ks++) {
            s16x8 a[4], b[4];
            #pragma unroll
            for (int mt = 0; mt < 4; mt++) {
                int row = wr*64 + mt*16 + l15;
                a[mt] = *(const s16x8*)((const char*)As + row * 128 + ((ks*4 + quad + row) & 7) * 16);
            }
            #pragma unroll
            for (int nt = 0; nt < 4; nt++) {
                int row = wc*64 + nt*16 + l15;
                b[nt] = *(const s16x8*)((const char*)Bs + row * 128 + ((ks*4 + quad + row) & 7) * 16);
            }
            #pragma unroll
            for (int mt = 0; mt < 4; mt++)
                #pragma unroll
                for (int nt = 0; nt < 4; nt++)
                    acc[mt][nt] = __builtin_amdgcn_mfma_f32_16x16x32_bf16(a[mt], b[nt], acc[mt][nt], 0, 0, 0);
        }
    }
}

// ---------------------------------------------------------------------------
// QKV projections: z=0 -> q (scaled, [B,H,S,d]), z=1 -> k ([B,H,S,d]),
// z=2 -> V^T computed DIRECTLY as Wv * X^T (operand swap, coalesced stores).
// ---------------------------------------------------------------------------
__global__ __launch_bounds__(256) void qkv_gemm_kernel(
    unsigned short* __restrict__ ws,
    const float* __restrict__ bq, const float* __restrict__ bk, const float* __restrict__ bv)
{
    __shared__ __align__(16) unsigned short As[8192];
    __shared__ __align__(16) unsigned short Bs[8192];
    const int z = blockIdx.z;
    const unsigned short *A, *W;
    int r0, c0;
    if (z != 2) {
        A = ws + (size_t)z * 4194304;            // xq/xk
        W = ws + OFF_WQ + (size_t)z * 1048576;
        r0 = blockIdx.x * 128; c0 = blockIdx.y * 128;
    } else {
        A = ws + OFF_WV;                         // rows = output features
        W = ws + OFF_XV;                         // "cols" = seq rows
        r0 = blockIdx.y * 128; c0 = blockIdx.x * 128;
    }
    const float* bias = (z == 0) ? bq : (z == 1 ? bk : bv);
    unsigned short* outp = ws + OFF_QB + (size_t)z * 4194304;      // qb/kb/vt
    const float scale = (z == 0) ? QSCALE : 1.0f;

    f32x4 acc[4][4] = {};
    gemm_body(A, W, r0, c0, As, Bs, acc);

    const int lane = threadIdx.x & 63, wave = threadIdx.x >> 6;
    const int quad = lane >> 4, l15 = lane & 15;
    const int wr = wave >> 1, wc = wave & 1;
    if (z != 2) {
        float bias_v[4];
        #pragma unroll
        for (int nt = 0; nt < 4; nt++) bias_v[nt] = bias[c0 + wc*64 + nt*16 + l15];
        #pragma unroll
        for (int mt = 0; mt < 4; mt++) {
            #pragma unroll
            for (int nt = 0; nt < 4; nt++) {
                int c = c0 + wc*64 + nt*16 + l15;
                int hh = c >> 6, dd = c & 63;
                #pragma unroll
                for (int reg = 0; reg < 4; reg++) {
                    int r = r0 + wr*64 + mt*16 + quad*4 + reg;
                    int bb = r >> 11, ss = r & (SEQ - 1);
                    float val = (acc[mt][nt][reg] + bias_v[nt]) * scale;
                    outp[(((size_t)(bb*NHEAD + hh)) * SEQ + ss) * HDIM + dd] = f2bf(val);
                }
            }
        }
    } else {
        #pragma unroll
        for (int mt = 0; mt < 4; mt++) {
            #pragma unroll
            for (int reg = 0; reg < 4; reg++) {
                int f = r0 + wr*64 + mt*16 + quad*4 + reg;   // feature
                int hh = f >> 6, dd = f & 63;
                float bfv = bias[f];
                #pragma unroll
                for (int nt = 0; nt < 4; nt++) {
                    int r = c0 + wc*64 + nt*16 + l15;        // seq row
                    int bb = r >> 11, ss = r & (SEQ - 1);
                    outp[(((size_t)(bb*NHEAD + hh)) * HDIM + dd) * SEQ + ss] =
                        f2bf(acc[mt][nt][reg] + bfv);
                }
            }
        }
    }
}

// ---------------------------------------------------------------------------
// Out projection: out = ab @ Wo^T + bo + residual  (fp32 out)
// ---------------------------------------------------------------------------
__global__ __launch_bounds__(256) void oproj_gemm_kernel(
    const unsigned short* __restrict__ ws, const float* __restrict__ bo,
    const float* __restrict__ resid, float* __restrict__ outf)
{
    __shared__ __align__(16) unsigned short As[8192];
    __shared__ __align__(16) unsigned short Bs[8192];
    const unsigned short* A = ws + OFF_XQ;      // ab lives where xq was
    const unsigned short* W = ws + OFF_WO;
    const int r0 = blockIdx.x * 128, c0 = blockIdx.y * 128;

    f32x4 acc[4][4] = {};
    gemm_body(A, W, r0, c0, (unsigned short*)As, (unsigned short*)Bs, acc);

    const int lane = threadIdx.x & 63, wave = threadIdx.x >> 6;
    const int quad = lane >> 4, l15 = lane & 15;
    const int wr = wave >> 1, wc = wave & 1;
    #pragma unroll
    for (int mt = 0; mt < 4; mt++) {
        #pragma unroll
        for (int nt = 0; nt < 4; nt++) {
            int c = c0 + wc*64 + nt*16 + l15;
            float bv = bo[c];
            #pragma unroll
            for (int reg = 0; reg < 4; reg++) {
                int r = r0 + wr*64 + mt*16 + quad*4 + reg;
                size_t idx = (size_t)r * DMODEL + c;
                outf[idx] = acc[mt][nt][reg] + bv + resid[idx];
            }
        }
    }
}

// ---------------------------------------------------------------------------
// Flash attention, bf16 MFMA, static softmax (R5 version, proven stable).
// Block = 8 waves (512 thr), 128 q-rows; wave owns 16 q-rows. K/V^T 64-key
// chunks staged to LDS (global_load_lds, XOR-rotated rows, double-buffered).
// l via MFMA ones-column; P packed by truncation (bias cancels in P/l);
// per-(b,qb128) chunk summary -> zero mask loads when chunks are all-ones.
// ---------------------------------------------------------------------------
__global__ __launch_bounds__(512) void attn_mfma_kernel(
    const unsigned short* __restrict__ ws,
    const unsigned long long* __restrict__ cmask,
    const unsigned int* __restrict__ msum,
    unsigned short* __restrict__ ab)
{
    const int tid  = threadIdx.x;
    const int wave = tid >> 6, lane = tid & 63;
    const int quad = lane >> 4, l15 = lane & 15;
    const int h = blockIdx.y, b = blockIdx.z;
    const int qw = blockIdx.x * 128 + wave * 16;

    const char* qh = (const char*)(ws + OFF_QB + ((size_t)(b*NHEAD + h)) * SEQ * HDIM);
    const char* kh = (const char*)(ws + OFF_KB + ((size_t)(b*NHEAD + h)) * SEQ * HDIM);
    const char* vh = (const char*)(ws + OFF_VT + ((size_t)(b*NHEAD + h)) * SEQ * HDIM);

    __shared__ __align__(16) char Ks[2][8192];   // [key][d] rows, groups rotated
    __shared__ __align__(16) char Vs[2][8192];   // [d][key] rows, groups rotated
    __shared__ __align__(16) unsigned short Pl[8][16 * 72];
    unsigned short* Pw = Pl[wave];

    const unsigned int chunkflags = msum[(b << 4) | blockIdx.x];

    // staging: 512 threads x 16B = one 8KB buffer per call; row = tid>>3,
    // phys group tid&7 holds logical group ((tid&7) - row) & 7 (XOR-rotate)
    const int srow = tid >> 3;
    const int sgrp = ((tid & 7) - srow) & 7;

    #define STAGE(bf, k0)                                                       \
        do {                                                                    \
            gl_lds16(kh + (size_t)((k0) + srow) * 128 + sgrp * 16,              \
                     Ks[bf] + wave * 1024);                                     \
            gl_lds16(vh + (size_t)srow * 4096 + (size_t)(k0) * 2 + sgrp * 16,   \
                     Vs[bf] + wave * 1024);                                     \
        } while (0)

    s16x8 qa[2];
    #pragma unroll
    for (int ks = 0; ks < 2; ks++)
        qa[ks] = *(const s16x8*)(qh + (size_t)(qw + l15) * 128 + ks*64 + quad*16);

    s16x8 onesf;
    {
        short so = (short)0x3F80;  // bf16 1.0
        if (l15 == 0) onesf = (s16x8){so, so, so, so, so, so, so, so};
        else          onesf = (s16x8){0, 0, 0, 0, 0, 0, 0, 0};
    }

    f32x4 o[4], lsum = {0.f, 0.f, 0.f, 0.f};
    #pragma unroll
    for (int nt = 0; nt < 4; nt++) o[nt] = (f32x4){0.f, 0.f, 0.f, 0.f};

    STAGE(0, 0);
    int bf = 0;
    for (int k0 = 0; k0 < SEQ; k0 += 64) {
        __syncthreads();            // vmcnt(0): buf[bf] staged, buf[bf^1] free
        // prefetch next chunk into the other buffer
        if (k0 + 64 < SEQ) STAGE(bf ^ 1, k0 + 64);

        const char* Kb = Ks[bf];
        const char* Vb = Vs[bf];
        // --- S = Q K^T (exp2-domain, pre-scaled) ---
        f32x4 s[4];
        #pragma unroll
        for (int nt = 0; nt < 4; nt++) {
            int key = nt*16 + l15;
            s16x8 kf0 = *(const s16x8*)(Kb + key*128 + ((quad     + key) & 7) * 16);
            s16x8 kf1 = *(const s16x8*)(Kb + key*128 + ((4 + quad + key) & 7) * 16);
            f32x4 z = {0.f, 0.f, 0.f, 0.f};
            s[nt] = __builtin_amdgcn_mfma_f32_16x16x32_bf16(qa[0], kf0, z, 0, 0, 0);
            s[nt] = __builtin_amdgcn_mfma_f32_16x16x32_bf16(qa[1], kf1, s[nt], 0, 0, 0);
        }
        // --- mask (wave-uniform skip when this chunk is all-ones) ---
        if (chunkflags & (1u << (k0 >> 6))) {
            const unsigned long long* cmp =
                cmask + ((size_t)b*32 + (k0 >> 6)) * SEQ + qw + quad*4;
            #pragma unroll
            for (int reg = 0; reg < 4; reg++) {
                unsigned long long cm = cmp[reg];
                if (cm != ~0ull) {
                    #pragma unroll
                    for (int nt = 0; nt < 4; nt++) {
                        int n = nt*16 + l15;
                        if (!((cm >> n) & 1)) s[nt][reg] = -1e9f;
                    }
                }
            }
        }
        // --- P = exp2(S) -> LDS (bf16 trunc; bias cancels in P/l) ---
        #pragma unroll
        for (int nt = 0; nt < 4; nt++)
            #pragma unroll
            for (int reg = 0; reg < 4; reg++) {
                float pv = exp2f(s[nt][reg]);
                Pw[(quad*4 + reg) * 72 + nt*16 + l15] =
                    (unsigned short)(__builtin_bit_cast(unsigned int, pv) >> 16);
            }
        // --- O += P @ V ; l += P @ 1 (ones-column MFMA) ---
        #pragma unroll
        for (int ks = 0; ks < 2; ks++) {
            s16x8 pa = *(const s16x8*)((const char*)Pw + l15 * 144 + ks*64 + quad*16);
            lsum = __builtin_amdgcn_mfma_f32_16x16x32_bf16(pa, onesf, lsum, 0, 0, 0);
            #pragma unroll
            for (int nt = 0; nt < 4; nt++) {
                int d = nt*16 + l15;
                s16x8 vf = *(const s16x8*)(Vb + d*128 + ((ks*4 + quad + d) & 7) * 16);
                o[nt] = __builtin_amdgcn_mfma_f32_16x16x32_bf16(pa, vf, o[nt], 0, 0, 0);
            }
        }
        bf ^= 1;
    }
    #undef STAGE
    // --- epilogue: O / l -> ab [B,S,DMODEL] bf16 (l at lanes l15==0) ---
    #pragma unroll
    for (int reg = 0; reg < 4; reg++) {
        float lv = __shfl(lsum[reg], lane & 48);
        float inv = 1.f / lv;
        int sg = qw + quad*4 + reg;
        #pragma unroll
        for (int nt = 0; nt < 4; nt++) {
            size_t idx = ((size_t)b * SEQ + sg) * DMODEL + h*HDIM + nt*16 + l15;
            ab[idx] = f2bf(o[nt][reg] * inv);
        }
    }
}

// ---------------------------------------------------------------------------
// LayerNorm (unbiased std, (std+eps) denominator), in-place on fp32 rows
// ---------------------------------------------------------------------------
__global__ __launch_bounds__(256) void ln_kernel(
    float* __restrict__ x, const float* __restrict__ gamma,
    const float* __restrict__ beta)
{
    const int row = blockIdx.x;
    const int tid = threadIdx.x;
    float4 vals = *(const float4*)&x[(size_t)row * DMODEL + tid * 4];
    float s  = vals.x + vals.y + vals.z + vals.w;
    float ss = vals.x*vals.x + vals.y*vals.y + vals.z*vals.z + vals.w*vals.w;
    #pragma unroll
    for (int off = 32; off > 0; off >>= 1) {
        s  += __shfl_down(s, off);
        ss += __shfl_down(ss, off);
    }
    __shared__ float sbuf[4], ssbuf[4];
    __shared__ float mean_s, inv_s;
    if ((tid & 63) == 0) { sbuf[tid >> 6] = s; ssbuf[tid >> 6] = ss; }
    __syncthreads();
    if (tid == 0) {
        float S1 = 0.f, S2 = 0.f;
        #pragma unroll
        for (int i = 0; i < 4; i++) { S1 += sbuf[i]; S2 += ssbuf[i]; }
        float mean = S1 * (1.0f / DMODEL);
        float var  = (S2 - (float)DMODEL * mean * mean) * (1.0f / (DMODEL - 1));
        float sd   = sqrtf(fmaxf(var, 0.f));
        mean_s = mean;
        inv_s  = 1.f / (sd + EPS);
    }
    __syncthreads();
    float4 g  = *(const float4*)&gamma[tid * 4];
    float4 bt = *(const float4*)&beta[tid * 4];
    float4 o;
    o.x = g.x * (vals.x - mean_s) * inv_s + bt.x;
    o.y = g.y * (vals.y - mean_s) * inv_s + bt.y;
    o.z = g.z * (vals.z - mean_s) * inv_s + bt.z;
    o.w = g.w * (vals.w - mean_s) * inv_s + bt.w;
    *(float4*)&x[(size_t)row * DMODEL + tid * 4] = o;
}

extern "C" void kernel_launch(void* const* d_in, const int* in_sizes, int n_in,
                              void* d_out, int out_size, void* d_ws, size_t ws_size,
                              hipStream_t stream) {
    const float* query = (const float*)d_in[0];
    const float* key   = (const float*)d_in[1];
    const float* value = (const float*)d_in[2];
    const int*   mask  = (const int*)d_in[3];
    const float* Wq = (const float*)d_in[4];  const float* bq = (const float*)d_in[5];
    const float* Wk = (const float*)d_in[6];  const float* bk = (const float*)d_in[7];
    const float* Wv = (const float*)d_in[8];  const float* bv = (const float*)d_in[9];
    const float* Wo = (const float*)d_in[10]; const float* bo = (const float*)d_in[11];
    const float* gamma = (const float*)d_in[12];
    const float* beta  = (const float*)d_in[13];
    float* out = (float*)d_out;

    unsigned short* ws = (unsigned short*)d_ws;
    unsigned long long* cmask = (unsigned long long*)(ws + OFF_CM);
    unsigned int* msum = (unsigned int*)(ws + OFF_MS);

    conv_all_kernel<<<16384, 256, 0, stream>>>(query, key, value, Wq, Wk, Wv, Wo, ws);
    mask_compress_kernel<<<512, 256, 0, stream>>>(mask, cmask, msum);
    qkv_gemm_kernel<<<dim3(32, 8, 3), 256, 0, stream>>>(ws, bq, bk, bv);
    attn_mfma_kernel<<<dim3(SEQ/128, NHEAD, BATCH), 512, 0, stream>>>(ws, cmask, msum, ws + OFF_XQ);
    oproj_gemm_kernel<<<dim3(32, 8), 256, 0, stream>>>(ws, bo, query, out);
    ln_kernel<<<NROWS, 256, 0, stream>>>(out, gamma, beta);
}